// Round 3
// baseline (626.073 us; speedup 1.0000x reference)
//
#include <hip/hip_runtime.h>

// SparseResidualBlock on MI355X (gfx950). Round 3: fuse elementwise passes
// into the convs. tmp tensors stored fp16 (pre-BN; BN stats exact from fp32
// accumulators). conv1 gathers fp32 x with in-staging fp16 convert; conv2
// applies BN1+ReLU in fp16 during its A-gather staging (hoisted per-lane
// scale/bias octets). Kills tohalf + bn_relu_tohalf passes (~460 MB traffic)
// and halves conv writes. 6 kernels total.

#define N_ACT 300000
#define NTAP  9
#define EPSV  1e-4f

using f16x8 = __attribute__((ext_vector_type(8))) _Float16;
using f32x4 = __attribute__((ext_vector_type(4))) float;

// ---- workspace layout (bytes) ----
#define OFF_T1    0UL                    // 76,800,000 : fp16 conv1 out (pre-BN)
#define OFF_T2    76800000UL             // 76,800,000 : fp16 conv2 out (pre-BN)
#define OFF_W1    153600000UL            // 294,912 : 9 taps x 2 chunks x 128 n x 64 k fp16
#define OFF_W2    (OFF_W1 + 294912UL)
#define OFF_STATS (OFF_W2 + 294912UL)    // 512 floats: sum1, sq1, sum2, sq2
#define OFF_SB1H  (OFF_STATS + 2048UL)   // sc1h[128] + bs1h[128] fp16 (512 B)
#define OFF_SB2   (OFF_SB1H + 512UL)     // sc2[128] + bs2[128] fp32 (1024 B)
// total ~154 MB

__device__ __forceinline__ unsigned short f2h(float v) {
  _Float16 h = (_Float16)v;               // RNE
  return __builtin_bit_cast(unsigned short, h);
}
__device__ __forceinline__ float h2f(unsigned short u) {
  return (float)__builtin_bit_cast(_Float16, u);
}

// ---- prep: fp16 + transpose + xor-seg-swizzle weights; zero stats ----
// image[(tap*2+ch)*8192 + n*64 + s*8 + j] = W[tap][ch*64 + 8*(s^(n&7)) + j][n]
__global__ void prep_kernel(const float* __restrict__ W1, const float* __restrict__ W2,
                            unsigned short* __restrict__ w1, unsigned short* __restrict__ w2,
                            float* __restrict__ zstats) {
  int b = blockIdx.x, t = threadIdx.x;
  if (b == 36) {                          // stats (512 floats) zeroing
    for (int i = t; i < 512; i += 256) zstats[i] = 0.f;
    return;
  }
  int w = b / 18, rem = b % 18;
  int tap = rem >> 1, ch = rem & 1;
  const float* W = w ? W2 : W1;
  unsigned short* o = w ? w2 : w1;
  int n  = t >> 1;
  int s0 = (t & 1) * 4;
  for (int s = s0; s < s0 + 4; ++s) {
    int sigma = s ^ (n & 7);
    for (int j = 0; j < 8; ++j) {
      int   k = ch * 64 + sigma * 8 + j;
      o[rem * 8192 + n * 64 + s * 8 + j] = f2h(W[tap * 16384 + k * 128 + n]);
    }
  }
}

// ---- gathered GEMM conv ----
// MODE 0: A source = fp32 x, staging transform = cvt to fp16.
// MODE 1: A source = fp16 tmp1, staging transform = relu(v*sc + bs) in fp16.
template <int MODE>
__global__ __launch_bounds__(256, 3)
void conv_kernel(const void* __restrict__ srcv, const int* __restrict__ nbr,
                 const unsigned short* __restrict__ wH,
                 const unsigned short* __restrict__ sbh,      // MODE1: sc[128],bs[128] fp16
                 unsigned short* __restrict__ outp,           // fp16 out (pre-BN)
                 float* __restrict__ ssum, float* __restrict__ ssq) {
  // LDS: A [0,16K) B [16K,32K).  A row r: seg s holds global k-seg (s ^ (r&7)).
  __shared__ char smem[32768];
  const int t  = threadIdx.x;
  const int wv = t >> 6, ln = t & 63;
  const int m0 = blockIdx.x * 128;
  const int rs = ln >> 3, sg = ln & 7;      // staging coords
  const int lane16 = ln & 15, g = ln >> 4;  // mfma frag coords
  const int sigma8 = (sg ^ rs) * 8;         // this lane's global channel octet (const: r&7==rs)

  const f16x8 zero8 = {0, 0, 0, 0, 0, 0, 0, 0};

  // hoisted BN tables (MODE 1): per-lane octets for ch=0 / ch=1
  f16x8 scv0 = zero8, scv1 = zero8, bsv0 = zero8, bsv1 = zero8;
  if (MODE == 1) {
    scv0 = *(const f16x8*)(sbh + sigma8);
    scv1 = *(const f16x8*)(sbh + 64 + sigma8);
    bsv0 = *(const f16x8*)(sbh + 128 + sigma8);
    bsv1 = *(const f16x8*)(sbh + 192 + sigma8);
  }

  f32x4 acc[16];
#pragma unroll
  for (int i = 0; i < 16; ++i) acc[i] = f32x4{0.f, 0.f, 0.f, 0.f};

  for (int tap = 0; tap < NTAP; ++tap) {
    int idx4[4];
#pragma unroll
    for (int it = 0; it < 4; ++it) {
      int gm = m0 + wv * 32 + it * 8 + rs;
      idx4[it] = (gm < N_ACT) ? nbr[gm * 9 + tap] : -1;
    }
#pragma unroll
    for (int ch = 0; ch < 2; ++ch) {
      __syncthreads();   // previous chunk's frag reads done before overwrite
      // ---- stage A (gather + transform, VALU path) ----
#pragma unroll
      for (int it = 0; it < 4; ++it) {
        int r   = wv * 32 + it * 8 + rs;
        int idx = idx4[it];
        long safe = (long)(idx < 0 ? 0 : idx);
        f16x8 y;
        if (MODE == 0) {
          const float* s = (const float*)srcv + safe * 128 + ch * 64 + sigma8;
          float4 a = *(const float4*)s;
          float4 b = *(const float4*)(s + 4);
          y[0] = (_Float16)a.x; y[1] = (_Float16)a.y; y[2] = (_Float16)a.z; y[3] = (_Float16)a.w;
          y[4] = (_Float16)b.x; y[5] = (_Float16)b.y; y[6] = (_Float16)b.z; y[7] = (_Float16)b.w;
        } else {
          const unsigned short* s = (const unsigned short*)srcv + safe * 128 + ch * 64 + sigma8;
          f16x8 v  = *(const f16x8*)s;
          f16x8 sc = ch ? scv1 : scv0;
          f16x8 bs = ch ? bsv1 : bsv0;
#pragma unroll
          for (int j = 0; j < 8; ++j) {
            _Float16 z = v[j] * sc[j] + bs[j];
            y[j] = z > (_Float16)0 ? z : (_Float16)0;
          }
        }
        if (idx < 0) y = zero8;              // reference: missing neighbor contributes 0
        *(f16x8*)(smem + r * 128 + sg * 16) = y;   // ds_write_b128
      }
      // ---- stage B (pre-swizzled 16KB image) via DMA ----
      {
        const char* gb = (const char*)wH + (tap * 2 + ch) * 16384;
#pragma unroll
        for (int it = 0; it < 4; ++it) {
          int o = wv * 4096 + it * 1024 + ln * 16;
          __builtin_amdgcn_global_load_lds((const __attribute__((address_space(1))) void*)(gb + o),
                                           (__attribute__((address_space(3))) void*)(smem + 16384 + o), 16, 0, 0);
        }
      }
      __syncthreads();   // drains vmcnt (B DMA) + lgkm (A writes)
      // ---- compute ----
#pragma unroll
      for (int ks = 0; ks < 2; ++ks) {
        f16x8 ah[4], bh[4];
        int sigma = ks * 4 + g;
#pragma unroll
        for (int mt = 0; mt < 4; ++mt) {
          int m = (wv & 1) * 64 + mt * 16 + lane16;
          ah[mt] = *(const f16x8*)(smem + m * 128 + ((sigma ^ (m & 7)) * 16));
        }
#pragma unroll
        for (int nt = 0; nt < 4; ++nt) {
          int n = (wv >> 1) * 64 + nt * 16 + lane16;
          bh[nt] = *(const f16x8*)(smem + 16384 + n * 128 + ((sigma ^ (n & 7)) * 16));
        }
#pragma unroll
        for (int mt = 0; mt < 4; ++mt)
#pragma unroll
          for (int nt = 0; nt < 4; ++nt)
            acc[mt * 4 + nt] = __builtin_amdgcn_mfma_f32_16x16x32_f16(ah[mt], bh[nt], acc[mt * 4 + nt], 0, 0, 0);
      }
    }
  }
  // ---- epilogue: fp16 store + per-channel sum/sumsq (pad rows are exactly 0) ----
  int rowbase = m0 + (wv & 1) * 64;
  int colbase = (wv >> 1) * 64;
  float s[4], q[4];
#pragma unroll
  for (int nt = 0; nt < 4; ++nt) { s[nt] = 0.f; q[nt] = 0.f; }
#pragma unroll
  for (int mt = 0; mt < 4; ++mt)
#pragma unroll
    for (int nt = 0; nt < 4; ++nt)
#pragma unroll
      for (int r = 0; r < 4; ++r) {
        float v  = acc[mt * 4 + nt][r];
        int  row = rowbase + mt * 16 + g * 4 + r;
        int  col = colbase + nt * 16 + lane16;
        if (row < N_ACT) outp[row * 128 + col] = f2h(v);
        s[nt] += v; q[nt] += v * v;
      }
  __syncthreads();
  float* sbuf = (float*)smem;           // [4 waves][64 cols]
  float* qbuf = ((float*)smem) + 256;
#pragma unroll
  for (int nt = 0; nt < 4; ++nt) {
    float sv = s[nt], qv = q[nt];
    sv += __shfl_xor(sv, 16, 64); sv += __shfl_xor(sv, 32, 64);
    qv += __shfl_xor(qv, 16, 64); qv += __shfl_xor(qv, 32, 64);
    if (ln < 16) { sbuf[wv * 64 + nt * 16 + ln] = sv; qbuf[wv * 64 + nt * 16 + ln] = qv; }
  }
  __syncthreads();
  if (t < 128) {
    int c = t;
    float tot = (c < 64) ? (sbuf[c] + sbuf[64 + c]) : (sbuf[128 + (c - 64)] + sbuf[192 + (c - 64)]);
    atomicAdd(ssum + c, tot);
  } else {
    int c = t - 128;
    float tot = (c < 64) ? (qbuf[c] + qbuf[64 + c]) : (qbuf[128 + (c - 64)] + qbuf[192 + (c - 64)]);
    atomicAdd(ssq + c, tot);
  }
}

// ---- fold stats into fp16 scale/bias tables (feeds conv2's fused BN) ----
__global__ void finalize1_kernel(const float* __restrict__ ssum, const float* __restrict__ ssq,
                                 const float* __restrict__ gamma, const float* __restrict__ beta,
                                 unsigned short* __restrict__ sbh) {
  int c = threadIdx.x;
  float mean = ssum[c] * (1.f / N_ACT);
  float var  = ssq[c] * (1.f / N_ACT) - mean * mean;
  float sc   = rsqrtf(var + EPSV) * gamma[c];
  sbh[c]       = f2h(sc);
  sbh[128 + c] = f2h(beta[c] - mean * sc);
}

// ---- fold stats into fp32 scale/bias (feeds final) ----
__global__ void finalize2_kernel(const float* __restrict__ ssum, const float* __restrict__ ssq,
                                 const float* __restrict__ gamma, const float* __restrict__ beta,
                                 float* __restrict__ scale, float* __restrict__ bias) {
  int c = threadIdx.x;
  float mean = ssum[c] * (1.f / N_ACT);
  float var  = ssq[c] * (1.f / N_ACT) - mean * mean;
  float sc   = rsqrtf(var + EPSV) * gamma[c];
  scale[c] = sc;
  bias[c]  = beta[c] - mean * sc;
}

// ---- BN2 + residual + ReLU (tmp2 is fp16) ----
__global__ void final_kernel(const unsigned short* __restrict__ t2,
                             const float* __restrict__ scale, const float* __restrict__ bias,
                             const float* __restrict__ x, float* __restrict__ outp) {
  int i = (blockIdx.x * 256 + threadIdx.x) * 4;
  int c = i & 127;
  ushort4 hv = *(const ushort4*)(t2 + i);
  float4 sc  = *(const float4*)(scale + c);
  float4 bs  = *(const float4*)(bias + c);
  float4 xx  = *(const float4*)(x + i);
  float4 o;
  o.x = fmaxf(h2f(hv.x) * sc.x + bs.x + xx.x, 0.f);
  o.y = fmaxf(h2f(hv.y) * sc.y + bs.y + xx.y, 0.f);
  o.z = fmaxf(h2f(hv.z) * sc.z + bs.z + xx.z, 0.f);
  o.w = fmaxf(h2f(hv.w) * sc.w + bs.w + xx.w, 0.f);
  *(float4*)(outp + i) = o;
}

extern "C" void kernel_launch(void* const* d_in, const int* in_sizes, int n_in,
                              void* d_out, int out_size, void* d_ws, size_t ws_size,
                              hipStream_t stream) {
  const float* x   = (const float*)d_in[0];
  const int*   nbr = (const int*)d_in[1];
  const float* W1  = (const float*)d_in[2];
  const float* g1  = (const float*)d_in[3];
  const float* b1  = (const float*)d_in[4];
  const float* W2  = (const float*)d_in[5];
  const float* g2  = (const float*)d_in[6];
  const float* b2  = (const float*)d_in[7];
  float* out = (float*)d_out;
  char*  ws  = (char*)d_ws;

  unsigned short* t1  = (unsigned short*)(ws + OFF_T1);
  unsigned short* t2  = (unsigned short*)(ws + OFF_T2);
  unsigned short* w1  = (unsigned short*)(ws + OFF_W1);
  unsigned short* w2  = (unsigned short*)(ws + OFF_W2);
  float*          st  = (float*)(ws + OFF_STATS);     // sum1, sq1, sum2, sq2 (128 each)
  unsigned short* sbh = (unsigned short*)(ws + OFF_SB1H);
  float*          sc2 = (float*)(ws + OFF_SB2);
  float*          bs2 = sc2 + 128;

  prep_kernel<<<37, 256, 0, stream>>>(W1, W2, w1, w2, st);
  conv_kernel<0><<<2344, 256, 0, stream>>>(x, nbr, w1, nullptr, t1, st, st + 128);
  finalize1_kernel<<<1, 128, 0, stream>>>(st, st + 128, g1, b1, sbh);
  conv_kernel<1><<<2344, 256, 0, stream>>>(t1, nbr, w2, sbh, t2, st + 256, st + 384);
  finalize2_kernel<<<1, 128, 0, stream>>>(st + 256, st + 384, g2, b2, sc2, bs2);
  final_kernel<<<37500, 256, 0, stream>>>(t2, sc2, bs2, x, out);
}